// Round 9
// baseline (248.640 us; speedup 1.0000x reference)
//
#include <hip/hip_runtime.h>
#include <math.h>

#define HWSZ 6400
#define WIMG 80
#define HIMG 80
#define BEPS 1e-5f

typedef __attribute__((ext_vector_type(8))) short short8;
typedef __attribute__((ext_vector_type(4))) float f32x4;
typedef __attribute__((ext_vector_type(4))) unsigned u32x4;

__device__ __forceinline__ unsigned short f2b(float f) {
    unsigned u = __builtin_bit_cast(unsigned, f);
    u += 0x7fffu + ((u >> 16) & 1u);
    return (unsigned short)(u >> 16);
}
__device__ __forceinline__ float silu_f(float t) { return t / (1.f + __expf(-t)); }

#define BMFMA(a, b, c) __builtin_amdgcn_mfma_f32_16x16x32_bf16(a, b, c, 0, 0, 0)

// async global->LDS DMA, 16B per lane; LDS dest = wave-uniform base + lane*16
__device__ __forceinline__ void gload16(const unsigned short* g, unsigned short* l) {
    __builtin_amdgcn_global_load_lds(
        (const __attribute__((address_space(1))) unsigned int*)g,
        (__attribute__((address_space(3))) unsigned int*)l, 16, 0, 0);
}

// ---------------- prep: BN-fold + bf16 A-fragment prepack -------------------
// apko [36 ks][2 mi][64][8], apkd [36 ks][8 mt][64][8], apk2 [4 ks][16 mt][64][8]
__global__ __launch_bounds__(256) void k_prep(
    const float* __restrict__ cv1w, const float* __restrict__ g1, const float* __restrict__ b1,
    const float* __restrict__ m1, const float* __restrict__ v1,
    const float* __restrict__ offw, const float* __restrict__ offb,
    const float* __restrict__ dcnw, const float* __restrict__ dcnb,
    const float* __restrict__ g2, const float* __restrict__ b2,
    const float* __restrict__ m2, const float* __restrict__ v2,
    const float* __restrict__ cv2w, const float* __restrict__ g3, const float* __restrict__ b3,
    const float* __restrict__ m3, const float* __restrict__ v3,
    unsigned short* __restrict__ apk1, unsigned short* __restrict__ apko,
    unsigned short* __restrict__ apkd, unsigned short* __restrict__ apk2,
    float* __restrict__ bias1, float* __restrict__ biaso,
    float* __restrict__ bias2, float* __restrict__ bias3)
{
    int idx = blockIdx.x * 256 + threadIdx.x;
    if (idx < 32768) {                       // cv1: [8 mt][8 ks][64][8], K = 256 ch
        int j = idx & 7, L = (idx >> 3) & 63, ks = (idx >> 9) & 7, mt = idx >> 12;
        int o = mt * 16 + (L & 15), k = ks * 32 + (L >> 4) * 8 + j;
        float inv = g1[o] * rsqrtf(v1[o] + BEPS);
        apk1[idx] = f2b(cv1w[o * 256 + k] * inv);
    } else if (idx < 69632) {                // off -> [ks][mi]
        int t = idx - 32768;
        int j = t & 7, L = (t >> 3) & 63;
        int mt = t / 18432, rem = t % 18432, ks = rem >> 9;
        int o = mt * 16 + (L & 15);
        int kp = ks * 32 + (L >> 4) * 8 + j;
        int n = kp >> 7, c = kp & 127;
        float wv = (o < 27) ? offw[(size_t)(o * 128 + c) * 9 + n] : 0.f;
        apko[((size_t)(ks * 2 + mt) * 64 + L) * 8 + j] = f2b(wv);
    } else if (idx < 217088) {               // dcn -> [ks][mt], BN2 fold
        int t = idx - 69632;
        int j = t & 7, L = (t >> 3) & 63;
        int mt = t / 18432, rem = t % 18432, ks = rem >> 9;
        int o = mt * 16 + (L & 15);
        int kp = ks * 32 + (L >> 4) * 8 + j;
        int n = kp >> 7, c = kp & 127;
        float inv = g2[o] * rsqrtf(v2[o] + BEPS);
        apkd[((size_t)(ks * 8 + mt) * 64 + L) * 8 + j] = f2b(dcnw[(size_t)(o * 128 + c) * 9 + n] * inv);
    } else if (idx < 249856) {               // cv2 -> [ks][mt], BN3 fold
        int t = idx - 217088;
        int j = t & 7, L = (t >> 3) & 63, ks = (t >> 9) & 3, mt = t >> 11;
        int o = mt * 16 + (L & 15), k = ks * 32 + (L >> 4) * 8 + j;
        float inv = g3[o] * rsqrtf(v3[o] + BEPS);
        apk2[((size_t)(ks * 16 + mt) * 64 + L) * 8 + j] = f2b(cv2w[o * 128 + k] * inv);
    } else if (idx < 250395) {               // biases
        int t = idx - 249856;
        if (t < 128) { float inv = g1[t] * rsqrtf(v1[t] + BEPS); bias1[t] = b1[t] - m1[t] * inv; }
        else if (t < 155) { biaso[t - 128] = offb[t - 128]; }
        else if (t < 283) { int o = t - 155; float inv = g2[o] * rsqrtf(v2[o] + BEPS);
                            bias2[o] = dcnb[o] * inv + b2[o] - m2[o] * inv; }
        else { int o = t - 283; float inv = g3[o] * rsqrtf(v3[o] + BEPS); bias3[o] = b3[o] - m3[o] * inv; }
    }
}

// ---------------- cv1: 1x1 (256->128) + bn1 + silu -> y1t (pixel-major bf16) ----
__global__ __launch_bounds__(256) void k_cv1(
    const float* __restrict__ x, const unsigned short* __restrict__ apk1,
    const float* __restrict__ bias1, unsigned short* __restrict__ y1t)
{
    __shared__ __align__(16) unsigned short sB[20480];
    int blk = blockIdx.x;
    int b = blk / 100, pt = blk % 100;
    int p0 = pt * 64;
    int tid = threadIdx.x;
    int lane = tid & 63;
    int w = tid >> 6;
    // hoist all 16 A-fragments (64 KB table, L2-hot) into registers
    short8 af0[8], af1[8];
#pragma unroll
    for (int ks = 0; ks < 8; ++ks) {
        af0[ks] = *(const short8*)&apk1[(size_t)(((w * 2 + 0) * 8 + ks) * 64 + lane) * 8];
        af1[ks] = *(const short8*)&apk1[(size_t)(((w * 2 + 1) * 8 + ks) * 64 + lane) * 8];
    }
    {
        int px = lane, q = w;
        const float* xb = x + (size_t)b * 256 * HWSZ + p0 + px;
        for (int ks = 0; ks < 8; ++ks) {
            short8 v;
#pragma unroll
            for (int j = 0; j < 8; ++j)
                v[j] = (short)f2b(xb[(size_t)(ks * 32 + q * 8 + j) * HWSZ]);
            *(short8*)&sB[((ks * 4 + (px >> 4)) * 16 + (px & 15)) * 40 + q * 8] = v;
        }
    }
    __syncthreads();
    int n16 = lane & 15, qd = lane >> 4;
    f32x4 acc[2][4];
#pragma unroll
    for (int mi = 0; mi < 2; ++mi)
#pragma unroll
        for (int nt = 0; nt < 4; ++nt) acc[mi][nt] = (f32x4){0.f, 0.f, 0.f, 0.f};
#pragma unroll
    for (int ks = 0; ks < 8; ++ks) {
        short8 bf[4];
#pragma unroll
        for (int nt = 0; nt < 4; ++nt)
            bf[nt] = *(const short8*)&sB[((ks * 4 + nt) * 16 + n16) * 40 + qd * 8];
#pragma unroll
        for (int nt = 0; nt < 4; ++nt) acc[0][nt] = BMFMA(af0[ks], bf[nt], acc[0][nt]);
#pragma unroll
        for (int nt = 0; nt < 4; ++nt) acc[1][nt] = BMFMA(af1[ks], bf[nt], acc[1][nt]);
    }
    __syncthreads();
#pragma unroll
    for (int mi = 0; mi < 2; ++mi)
#pragma unroll
        for (int nt = 0; nt < 4; ++nt)
#pragma unroll
            for (int r = 0; r < 4; ++r) {
                int o = w * 32 + mi * 16 + qd * 4 + r;
                float sv = silu_f(acc[mi][nt][r] + bias1[o]);
                sB[(nt * 16 + n16) * 136 + o] = f2b(sv);
            }
    __syncthreads();
    {
        int px = tid >> 2, qq = tid & 3;
        unsigned short* ytb = y1t + ((size_t)b * HWSZ + p0 + px) * 128;
#pragma unroll
        for (int seg = 0; seg < 4; ++seg) {
            short8 v = *(const short8*)&sB[px * 136 + qq * 32 + seg * 8];
            *(short8*)&ytb[qq * 32 + seg * 8] = v;
        }
    }
}

// ---------------- odc: fused off + DCNv2 + bn2 + silu + cv2 + residual -------
// af slabs stream via global_load_lds ping-pong with counted vmcnt(2) across
// raw barriers. FIX vs r8: lgkmcnt(0) drained BEFORE B1 (cross-lane ds_write
// handoffs: sRaw, sZ) and sched_barrier(0) after B2 (no ds_read hoist).
#define NSLAB 53

#define ACC8(uu, cb)                                                                   \
    {                                                                                  \
        _Pragma("unroll") for (int t = 0; t < 4; ++t) {                                \
            unsigned uv = (uu)[t];                                                     \
            av[(cb) + 2 * t] = fmaf(wk, __builtin_bit_cast(float, uv << 16),           \
                                    av[(cb) + 2 * t]);                                 \
            av[(cb) + 2 * t + 1] = fmaf(wk, __builtin_bit_cast(float, uv & 0xffff0000u),\
                                        av[(cb) + 2 * t + 1]);                         \
        }                                                                              \
    }

__device__ __forceinline__ const unsigned short* slab_src(
    const unsigned short* apko, const unsigned short* apkd,
    const unsigned short* apk2, int i) {
    if (i < 9)  return apko + (size_t)i * 4096;
    if (i < 45) return apkd + (size_t)(i - 9) * 4096;
    return apk2 + (size_t)(i - 45) * 4096;
}

#define STAGE(i, bp)                                                                   \
    {                                                                                  \
        const unsigned short* src_ = slab_src(apko, apkd, apk2, (i));                  \
        gload16(src_ + ((w * 2 + 0) * 512 + lane * 8), &sAf[bp][(w * 2 + 0) * 512]);   \
        gload16(src_ + ((w * 2 + 1) * 512 + lane * 8), &sAf[bp][(w * 2 + 1) * 512]);   \
    }

// B1 (drain ds ops, all done reading buf) -> stage slab+2 into freed buf ->
// counted wait for own NEXT-slab DMAs -> B2 (next slab ready) -> fence.
#define SLAB_SYNC(slab)                                                                \
    {                                                                                  \
        asm volatile("s_waitcnt lgkmcnt(0)" ::: "memory");                             \
        __builtin_amdgcn_sched_barrier(0);                                             \
        __builtin_amdgcn_s_barrier();                                                  \
        if ((slab) + 2 < NSLAB) {                                                      \
            STAGE((slab) + 2, bufp)                                                    \
            asm volatile("s_waitcnt vmcnt(2)" ::: "memory");                           \
        } else {                                                                       \
            asm volatile("s_waitcnt vmcnt(0)" ::: "memory");                           \
        }                                                                              \
        __builtin_amdgcn_sched_barrier(0);                                             \
        __builtin_amdgcn_s_barrier();                                                  \
        __builtin_amdgcn_sched_barrier(0);                                             \
        bufp ^= 1;                                                                     \
    }

__global__ __launch_bounds__(256, 4) void k_odc(
    const unsigned short* __restrict__ y1t,
    const unsigned short* __restrict__ apko, const float* __restrict__ biaso,
    const unsigned short* __restrict__ apkd, const float* __restrict__ bias2,
    const unsigned short* __restrict__ apk2, const float* __restrict__ bias3,
    const float* __restrict__ x, float* __restrict__ out)
{
    __shared__ float sRaw[27 * 66];                          //  7,128 B
    __shared__ __align__(16) unsigned short sAf[2][4096];    // 16,384 B af ping-pong
    __shared__ __align__(16) unsigned short sZ[64 * 132];    // 16,896 B z buffer

    int blk = blockIdx.x;
    int b = blk / 100, pt = blk % 100;
    int h0 = (pt / 5) * 4, w0 = (pt % 5) * 16;
    int tid = threadIdx.x, lane = tid & 63, w = tid >> 6;
    int n16 = lane & 15, qd = lane >> 4;
    int pxl = w * 16 + n16;
    const unsigned short* yb = y1t + (size_t)b * HWSZ * 128;

    // prologue: 2 slabs in flight, wait only for slab 0
    STAGE(0, 0)
    STAGE(1, 1)
    asm volatile("s_waitcnt vmcnt(2)" ::: "memory");
    __builtin_amdgcn_sched_barrier(0);
    __builtin_amdgcn_s_barrier();
    __builtin_amdgcn_sched_barrier(0);
    int bufp = 0;

    // ---- off phase: slabs 0..8 (one per tap); B-frags from global; raw -> LDS
    {
        f32x4 oa0 = (f32x4){0.f, 0.f, 0.f, 0.f};
        f32x4 oa1 = (f32x4){0.f, 0.f, 0.f, 0.f};
        for (int n = 0; n < 9; ++n) {
            int dh = n / 3 - 1, dw = n % 3 - 1;
            int hh = h0 + w + dh, ww = w0 + n16 + dw;
            bool valid = ((unsigned)hh < HIMG) && ((unsigned)ww < WIMG);
            int row = min(max(hh, 0), HIMG - 1) * WIMG + min(max(ww, 0), WIMG - 1);
            const unsigned short* ys = &yb[(size_t)row * 128 + qd * 8];
            short8 bfv[4];
#pragma unroll
            for (int s = 0; s < 4; ++s) {
                short8 v = *(const short8*)&ys[s * 32];
                if (!valid) v = (short8){0, 0, 0, 0, 0, 0, 0, 0};
                bfv[s] = v;
            }
#pragma unroll
            for (int s = 0; s < 4; ++s) {
                short8 a0 = *(const short8*)&sAf[bufp][(s * 2 + 0) * 512 + lane * 8];
                short8 a1 = *(const short8*)&sAf[bufp][(s * 2 + 1) * 512 + lane * 8];
                oa0 = BMFMA(a0, bfv[s], oa0);
                oa1 = BMFMA(a1, bfv[s], oa1);
            }
            if (n == 8) {
#pragma unroll
                for (int mi = 0; mi < 2; ++mi)
#pragma unroll
                    for (int r4 = 0; r4 < 4; ++r4) {
                        int o = mi * 16 + qd * 4 + r4;
                        if (o < 27) {
                            float t = (mi ? oa1[r4] : oa0[r4]) + biaso[o];
                            if (o >= 18) t = 1.f / (1.f + __expf(-t));
                            sRaw[o * 66 + pxl] = t;
                        }
                    }
            }
            SLAB_SYNC(n)
        }
    }

    // ---- dcn phase: slabs 9..44; bilinear gather from global y1t ----
    f32x4 acc[8];
#pragma unroll
    for (int mt = 0; mt < 8; ++mt) acc[mt] = (f32x4){0.f, 0.f, 0.f, 0.f};
    int hI = h0 + w, wI = w0 + n16;

    for (int n = 0; n < 9; ++n) {
        float av[32];
#pragma unroll
        for (int s = 0; s < 4; ++s) {
            int slab = 9 + n * 4 + s;
            if (s == 0) {
                float dy = sRaw[(2 * n) * 66 + pxl];
                float dx = sRaw[(2 * n + 1) * 66 + pxl];
                float mk = sRaw[(18 + n) * 66 + pxl];
                float py = (float)(hI - 1 + n / 3) + dy;
                float px = (float)(wI - 1 + n % 3) + dx;
                float y0f = floorf(py), x0f = floorf(px);
                float fy = py - y0f, fxv = px - x0f;
                int y0 = (int)y0f, x0 = (int)x0f;
                float wy0 = (1.f - fy) * mk, wy1 = fy * mk, fx1 = 1.f - fxv;
#pragma unroll
                for (int j = 0; j < 32; ++j) av[j] = 0.f;
#pragma unroll
                for (int k = 0; k < 4; ++k) {
                    int yy = y0 + (k >> 1), xx = x0 + (k & 1);
                    bool vld = ((unsigned)yy < HIMG) && ((unsigned)xx < WIMG);
                    float wk = ((k >> 1) ? wy1 : wy0) * ((k & 1) ? fxv : fx1);
                    if (!vld) wk = 0.f;
                    int yc = min(max(yy, 0), HIMG - 1);
                    int xc = min(max(xx, 0), WIMG - 1);
                    const unsigned short* src = &yb[(size_t)(yc * WIMG + xc) * 128 + qd * 8];
                    u32x4 u0 = *(const u32x4*)src;
                    u32x4 u1 = *(const u32x4*)(src + 32);
                    u32x4 u2 = *(const u32x4*)(src + 64);
                    u32x4 u3 = *(const u32x4*)(src + 96);
                    ACC8(u0, 0) ACC8(u1, 8) ACC8(u2, 16) ACC8(u3, 24)
                }
            }
            // pack this k-step's B-frag, 8 ds_read af + 8 MFMA
            unsigned pk0, pk1, pk2, pk3;
            asm("v_cvt_pk_bf16_f32 %0, %1, %2" : "=v"(pk0) : "v"(av[s * 8 + 0]), "v"(av[s * 8 + 1]));
            asm("v_cvt_pk_bf16_f32 %0, %1, %2" : "=v"(pk1) : "v"(av[s * 8 + 2]), "v"(av[s * 8 + 3]));
            asm("v_cvt_pk_bf16_f32 %0, %1, %2" : "=v"(pk2) : "v"(av[s * 8 + 4]), "v"(av[s * 8 + 5]));
            asm("v_cvt_pk_bf16_f32 %0, %1, %2" : "=v"(pk3) : "v"(av[s * 8 + 6]), "v"(av[s * 8 + 7]));
            short8 bfv = __builtin_bit_cast(short8, (u32x4){pk0, pk1, pk2, pk3});
#pragma unroll
            for (int mt = 0; mt < 8; ++mt) {
                short8 af = *(const short8*)&sAf[bufp][mt * 512 + lane * 8];
                acc[mt] = BMFMA(af, bfv, acc[mt]);
            }
            if (n == 8 && s == 3) {
                // z epilogue: bn2 + silu -> pixel-major bf16 into sZ
#pragma unroll
                for (int mt = 0; mt < 8; ++mt)
#pragma unroll
                    for (int r4 = 0; r4 < 4; ++r4) {
                        int o = mt * 16 + qd * 4 + r4;
                        float sv = silu_f(acc[mt][r4] + bias2[o]);
                        sZ[pxl * 132 + o] = f2b(sv);
                    }
            }
            SLAB_SYNC(slab)
        }
    }

    // ---- cv2 phase: slabs 45..52 (8 mt rows each) ----
    f32x4 c2[16];
#pragma unroll
    for (int mt = 0; mt < 16; ++mt) c2[mt] = (f32x4){0.f, 0.f, 0.f, 0.f};
#pragma unroll
    for (int h2 = 0; h2 < 8; ++h2) {
        int slab = 45 + h2;
        int ks = h2 >> 1, half = h2 & 1;
        short8 bf = *(const short8*)&sZ[pxl * 132 + ks * 32 + qd * 8];
#pragma unroll
        for (int mt = 0; mt < 8; ++mt) {
            short8 af = *(const short8*)&sAf[bufp][mt * 512 + lane * 8];
            c2[half * 8 + mt] = BMFMA(af, bf, c2[half * 8 + mt]);
        }
        SLAB_SYNC(slab)
    }
    int p = (h0 + w) * WIMG + w0 + n16;
    const float* xb = x + (size_t)b * 256 * HWSZ;
    float* ob = out + (size_t)b * 256 * HWSZ;
#pragma unroll
    for (int mt = 0; mt < 16; ++mt)
#pragma unroll
        for (int r4 = 0; r4 < 4; ++r4) {
            int o = mt * 16 + qd * 4 + r4;
            size_t idx = (size_t)o * HWSZ + p;
            ob[idx] = xb[idx] + silu_f(c2[mt][r4] + bias3[o]);
        }
}

extern "C" void kernel_launch(void* const* d_in, const int* in_sizes, int n_in,
                              void* d_out, int out_size, void* d_ws, size_t ws_size,
                              hipStream_t stream) {
    const float* x     = (const float*)d_in[0];
    const float* cv1w  = (const float*)d_in[1];
    const float* bn1g  = (const float*)d_in[2];
    const float* bn1b  = (const float*)d_in[3];
    const float* bn1m  = (const float*)d_in[4];
    const float* bn1v  = (const float*)d_in[5];
    const float* offw  = (const float*)d_in[6];
    const float* offb  = (const float*)d_in[7];
    const float* dcnw  = (const float*)d_in[8];
    const float* dcnb  = (const float*)d_in[9];
    const float* bn2g  = (const float*)d_in[10];
    const float* bn2b  = (const float*)d_in[11];
    const float* bn2m  = (const float*)d_in[12];
    const float* bn2v  = (const float*)d_in[13];
    const float* cv2w  = (const float*)d_in[14];
    const float* bn3g  = (const float*)d_in[15];
    const float* bn3b  = (const float*)d_in[16];
    const float* bn3m  = (const float*)d_in[17];
    const float* bn3v  = (const float*)d_in[18];
    float* out = (float*)d_out;

    // workspace layout (float units)
    float* base = (float*)d_ws;
    unsigned short* y1t = (unsigned short*)base;                 // 8*6400*128 bf16
    unsigned short* apk1 = (unsigned short*)(base + 7936000);
    unsigned short* apko = (unsigned short*)(base + 7952384);
    unsigned short* apkd = (unsigned short*)(base + 7970816);
    unsigned short* apk2 = (unsigned short*)(base + 8044544);
    float* bias1 = base + 8060928;
    float* biaso = base + 8061056;
    float* bias2 = base + 8061088;
    float* bias3 = base + 8061216;

    k_prep<<<979, 256, 0, stream>>>(cv1w, bn1g, bn1b, bn1m, bn1v,
                                    offw, offb, dcnw, dcnb,
                                    bn2g, bn2b, bn2m, bn2v,
                                    cv2w, bn3g, bn3b, bn3m, bn3v,
                                    apk1, apko, apkd, apk2,
                                    bias1, biaso, bias2, bias3);
    k_cv1<<<800, 256, 0, stream>>>(x, apk1, bias1, y1t);
    k_odc<<<800, 256, 0, stream>>>(y1t, apko, biaso, apkd, bias2,
                                   apk2, bias3, x, out);
}

// Round 10
// 245.262 us; speedup vs baseline: 1.0138x; 1.0138x over previous
//
#include <hip/hip_runtime.h>
#include <math.h>

#define HWSZ 6400
#define WIMG 80
#define HIMG 80
#define BEPS 1e-5f

typedef __attribute__((ext_vector_type(8))) short short8;
typedef __attribute__((ext_vector_type(4))) float f32x4;
typedef __attribute__((ext_vector_type(4))) unsigned u32x4;

__device__ __forceinline__ unsigned short f2b(float f) {
    unsigned u = __builtin_bit_cast(unsigned, f);
    u += 0x7fffu + ((u >> 16) & 1u);
    return (unsigned short)(u >> 16);
}
__device__ __forceinline__ float silu_f(float t) { return t / (1.f + __expf(-t)); }

#define BMFMA(a, b, c) __builtin_amdgcn_mfma_f32_16x16x32_bf16(a, b, c, 0, 0, 0)

// async global->LDS DMA, 16B per lane; LDS dest = wave-uniform base + lane*16
__device__ __forceinline__ void gload16(const unsigned short* g, unsigned short* l) {
    __builtin_amdgcn_global_load_lds(
        (const __attribute__((address_space(1))) unsigned int*)g,
        (__attribute__((address_space(3))) unsigned int*)l, 16, 0, 0);
}

// ---------------- prep: BN-fold + bf16 A-fragment prepack -------------------
// apko [36 ks][2 mi][64][8], apkd [36 ks][8 mt][64][8], apk2 [4 ks][16 mt][64][8]
__global__ __launch_bounds__(256) void k_prep(
    const float* __restrict__ cv1w, const float* __restrict__ g1, const float* __restrict__ b1,
    const float* __restrict__ m1, const float* __restrict__ v1,
    const float* __restrict__ offw, const float* __restrict__ offb,
    const float* __restrict__ dcnw, const float* __restrict__ dcnb,
    const float* __restrict__ g2, const float* __restrict__ b2,
    const float* __restrict__ m2, const float* __restrict__ v2,
    const float* __restrict__ cv2w, const float* __restrict__ g3, const float* __restrict__ b3,
    const float* __restrict__ m3, const float* __restrict__ v3,
    unsigned short* __restrict__ apk1, unsigned short* __restrict__ apko,
    unsigned short* __restrict__ apkd, unsigned short* __restrict__ apk2,
    float* __restrict__ bias1, float* __restrict__ biaso,
    float* __restrict__ bias2, float* __restrict__ bias3)
{
    int idx = blockIdx.x * 256 + threadIdx.x;
    if (idx < 32768) {                       // cv1: [8 mt][8 ks][64][8], K = 256 ch
        int j = idx & 7, L = (idx >> 3) & 63, ks = (idx >> 9) & 7, mt = idx >> 12;
        int o = mt * 16 + (L & 15), k = ks * 32 + (L >> 4) * 8 + j;
        float inv = g1[o] * rsqrtf(v1[o] + BEPS);
        apk1[idx] = f2b(cv1w[o * 256 + k] * inv);
    } else if (idx < 69632) {                // off -> [ks][mi]
        int t = idx - 32768;
        int j = t & 7, L = (t >> 3) & 63;
        int mt = t / 18432, rem = t % 18432, ks = rem >> 9;
        int o = mt * 16 + (L & 15);
        int kp = ks * 32 + (L >> 4) * 8 + j;
        int n = kp >> 7, c = kp & 127;
        float wv = (o < 27) ? offw[(size_t)(o * 128 + c) * 9 + n] : 0.f;
        apko[((size_t)(ks * 2 + mt) * 64 + L) * 8 + j] = f2b(wv);
    } else if (idx < 217088) {               // dcn -> [ks][mt], BN2 fold
        int t = idx - 69632;
        int j = t & 7, L = (t >> 3) & 63;
        int mt = t / 18432, rem = t % 18432, ks = rem >> 9;
        int o = mt * 16 + (L & 15);
        int kp = ks * 32 + (L >> 4) * 8 + j;
        int n = kp >> 7, c = kp & 127;
        float inv = g2[o] * rsqrtf(v2[o] + BEPS);
        apkd[((size_t)(ks * 8 + mt) * 64 + L) * 8 + j] = f2b(dcnw[(size_t)(o * 128 + c) * 9 + n] * inv);
    } else if (idx < 249856) {               // cv2 -> [ks][mt], BN3 fold
        int t = idx - 217088;
        int j = t & 7, L = (t >> 3) & 63, ks = (t >> 9) & 3, mt = t >> 11;
        int o = mt * 16 + (L & 15), k = ks * 32 + (L >> 4) * 8 + j;
        float inv = g3[o] * rsqrtf(v3[o] + BEPS);
        apk2[((size_t)(ks * 16 + mt) * 64 + L) * 8 + j] = f2b(cv2w[o * 128 + k] * inv);
    } else if (idx < 250395) {               // biases
        int t = idx - 249856;
        if (t < 128) { float inv = g1[t] * rsqrtf(v1[t] + BEPS); bias1[t] = b1[t] - m1[t] * inv; }
        else if (t < 155) { biaso[t - 128] = offb[t - 128]; }
        else if (t < 283) { int o = t - 155; float inv = g2[o] * rsqrtf(v2[o] + BEPS);
                            bias2[o] = dcnb[o] * inv + b2[o] - m2[o] * inv; }
        else { int o = t - 283; float inv = g3[o] * rsqrtf(v3[o] + BEPS); bias3[o] = b3[o] - m3[o] * inv; }
    }
}

// ---------------- cv1: 1x1 (256->128) + bn1 + silu -> y1t (pixel-major bf16) ----
// NEW staging: 16 x dwordx4 loads per wave (4 px x 1 ch per lane, 1 KB/instr
// coalesced) instead of 64 scalar 4B loads per thread. af hoisted to regs.
__global__ __launch_bounds__(256) void k_cv1(
    const float* __restrict__ x, const unsigned short* __restrict__ apk1,
    const float* __restrict__ bias1, unsigned short* __restrict__ y1t)
{
    __shared__ __align__(16) unsigned short sB[20480];
    int blk = blockIdx.x;
    int b = blk / 100, pt = blk % 100;
    int p0 = pt * 64;
    int tid = threadIdx.x;
    int lane = tid & 63;
    int w = tid >> 6;
    // hoist all 16 A-fragments (64 KB table, L2-hot) into registers
    short8 af0[8], af1[8];
#pragma unroll
    for (int ks = 0; ks < 8; ++ks) {
        af0[ks] = *(const short8*)&apk1[(size_t)(((w * 2 + 0) * 8 + ks) * 64 + lane) * 8];
        af1[ks] = *(const short8*)&apk1[(size_t)(((w * 2 + 1) * 8 + ks) * 64 + lane) * 8];
    }
    {
        // wave w stages channels [w*64, w*64+64): lane = (chl = lane>>4, pxg = lane&15)
        int pxg = lane & 15, chl = lane >> 4;
        const float* xb = x + (size_t)b * 256 * HWSZ + p0;
#pragma unroll
        for (int i = 0; i < 16; ++i) {
            int c = w * 64 + i * 4 + chl;
            f32x4 v = *(const f32x4*)&xb[(size_t)c * HWSZ + pxg * 4];
            int ks = c >> 5, q = (c >> 3) & 3, j = c & 7;
            int nt = pxg >> 2, nb = 4 * (pxg & 3);
#pragma unroll
            for (int e = 0; e < 4; ++e)
                sB[((ks * 4 + nt) * 16 + nb + e) * 40 + q * 8 + j] = f2b(v[e]);
        }
    }
    __syncthreads();
    int n16 = lane & 15, qd = lane >> 4;
    f32x4 acc[2][4];
#pragma unroll
    for (int mi = 0; mi < 2; ++mi)
#pragma unroll
        for (int nt = 0; nt < 4; ++nt) acc[mi][nt] = (f32x4){0.f, 0.f, 0.f, 0.f};
#pragma unroll
    for (int ks = 0; ks < 8; ++ks) {
        short8 bf[4];
#pragma unroll
        for (int nt = 0; nt < 4; ++nt)
            bf[nt] = *(const short8*)&sB[((ks * 4 + nt) * 16 + n16) * 40 + qd * 8];
#pragma unroll
        for (int nt = 0; nt < 4; ++nt) acc[0][nt] = BMFMA(af0[ks], bf[nt], acc[0][nt]);
#pragma unroll
        for (int nt = 0; nt < 4; ++nt) acc[1][nt] = BMFMA(af1[ks], bf[nt], acc[1][nt]);
    }
    __syncthreads();
#pragma unroll
    for (int mi = 0; mi < 2; ++mi)
#pragma unroll
        for (int nt = 0; nt < 4; ++nt)
#pragma unroll
            for (int r = 0; r < 4; ++r) {
                int o = w * 32 + mi * 16 + qd * 4 + r;
                float sv = silu_f(acc[mi][nt][r] + bias1[o]);
                sB[(nt * 16 + n16) * 136 + o] = f2b(sv);
            }
    __syncthreads();
    {
        int px = tid >> 2, qq = tid & 3;
        unsigned short* ytb = y1t + ((size_t)b * HWSZ + p0 + px) * 128;
#pragma unroll
        for (int seg = 0; seg < 4; ++seg) {
            short8 v = *(const short8*)&sB[px * 136 + qq * 32 + seg * 8];
            *(short8*)&ytb[qq * 32 + seg * 8] = v;
        }
    }
}

// ---------------- odc: fused off + DCNv2 + bn2 + silu + cv2 + residual -------
// REVERT to round-6 structure (best measured: 108.6 us): 8x20 halo staged once
// (XOR-swizzled), af slabs via global_load_lds ping-pong, plain __syncthreads.
#define HY2 8
#define HX2 20
#define NH 160
#define NSLAB 53

#define ACC8(uu, cb)                                                                   \
    {                                                                                  \
        _Pragma("unroll") for (int t = 0; t < 4; ++t) {                                \
            unsigned uv = (uu)[t];                                                     \
            av[(cb) + 2 * t] = fmaf(wk, __builtin_bit_cast(float, uv << 16),           \
                                    av[(cb) + 2 * t]);                                 \
            av[(cb) + 2 * t + 1] = fmaf(wk, __builtin_bit_cast(float, uv & 0xffff0000u),\
                                        av[(cb) + 2 * t + 1]);                         \
        }                                                                              \
    }

__device__ __forceinline__ const unsigned short* slab_src(
    const unsigned short* apko, const unsigned short* apkd,
    const unsigned short* apk2, int i) {
    if (i < 9)  return apko + (size_t)i * 4096;
    if (i < 45) return apkd + (size_t)(i - 9) * 4096;
    return apk2 + (size_t)(i - 45) * 4096;
}

#define STAGE(i, bp)                                                                   \
    {                                                                                  \
        const unsigned short* src_ = slab_src(apko, apkd, apk2, (i));                  \
        gload16(src_ + ((w * 2 + 0) * 512 + lane * 8), &sAf[bp][(w * 2 + 0) * 512]);   \
        gload16(src_ + ((w * 2 + 1) * 512 + lane * 8), &sAf[bp][(w * 2 + 1) * 512]);   \
    }

__global__ __launch_bounds__(256, 2) void k_odc(
    const unsigned short* __restrict__ y1t,
    const unsigned short* __restrict__ apko, const float* __restrict__ biaso,
    const unsigned short* __restrict__ apkd, const float* __restrict__ bias2,
    const unsigned short* __restrict__ apk2, const float* __restrict__ bias3,
    const float* __restrict__ x, float* __restrict__ out)
{
    __shared__ __align__(16) unsigned short sH[NH * 128];    // 40,960 B halo / z-buf
    __shared__ float sRaw[27 * 66];                          //  7,128 B
    __shared__ __align__(16) unsigned short sAf[2][4096];    // 16,384 B af ping-pong

    int blk = blockIdx.x;
    int b = blk / 100, pt = blk % 100;
    int h0 = (pt / 5) * 4, w0 = (pt % 5) * 16;
    int tid = threadIdx.x, lane = tid & 63, w = tid >> 6;
    int n16 = lane & 15, qd = lane >> 4;
    int pxl = w * 16 + n16;
    const unsigned short* yb = y1t + (size_t)b * HWSZ * 128;

    // ---- stage halo (8x20 rows, XOR-swizzled dest) + first af slab ----
    for (int i = tid; i < NH * 16; i += 256) {
        int r = i >> 4, u = i & 15;
        int ly = r / HX2, lx = r % HX2;
        int yy = min(max(h0 + ly - 2, 0), HIMG - 1);
        int xx = min(max(w0 + lx - 2, 0), WIMG - 1);
        *(u32x4*)&sH[r * 128 + ((u ^ (r & 7)) * 8)] =
            *(const u32x4*)&yb[(size_t)(yy * WIMG + xx) * 128 + u * 8];
    }
    STAGE(0, 0)
    __syncthreads();                          // halo + slab0 ready
    int bufp = 0;

    // ---- off phase: slabs 0..8 (one per tap); raw -> LDS ----
    {
        f32x4 oa0 = (f32x4){0.f, 0.f, 0.f, 0.f};
        f32x4 oa1 = (f32x4){0.f, 0.f, 0.f, 0.f};
        for (int n = 0; n < 9; ++n) {
            STAGE(n + 1, bufp ^ 1)
            int dh = n / 3 - 1, dw = n % 3 - 1;
            int hh = h0 + w + dh, ww = w0 + n16 + dw;
            bool valid = ((unsigned)hh < HIMG) && ((unsigned)ww < WIMG);
            int r = (w + 2 + dh) * HX2 + (n16 + 2 + dw);
            int xr = r & 7;
            const unsigned short* hb = &sH[r * 128];
#pragma unroll
            for (int s = 0; s < 4; ++s) {
                short8 bf = *(const short8*)&hb[((s * 4 + qd) ^ xr) * 8];
                if (!valid) bf = (short8){0, 0, 0, 0, 0, 0, 0, 0};
                short8 a0 = *(const short8*)&sAf[bufp][(s * 2 + 0) * 512 + lane * 8];
                short8 a1 = *(const short8*)&sAf[bufp][(s * 2 + 1) * 512 + lane * 8];
                oa0 = BMFMA(a0, bf, oa0);
                oa1 = BMFMA(a1, bf, oa1);
            }
            if (n == 8) {
#pragma unroll
                for (int mi = 0; mi < 2; ++mi)
#pragma unroll
                    for (int r4 = 0; r4 < 4; ++r4) {
                        int o = mi * 16 + qd * 4 + r4;
                        if (o < 27) {
                            float t = (mi ? oa1[r4] : oa0[r4]) + biaso[o];
                            if (o >= 18) t = 1.f / (1.f + __expf(-t));
                            sRaw[o * 66 + pxl] = t;
                        }
                    }
            }
            __syncthreads();
            bufp ^= 1;
        }
    }

    // ---- dcn phase: slabs 9..44; gather from LDS halo (global fallback) ----
    f32x4 acc[8];
#pragma unroll
    for (int mt = 0; mt < 8; ++mt) acc[mt] = (f32x4){0.f, 0.f, 0.f, 0.f};
    int hI = h0 + w, wI = w0 + n16;

    for (int n = 0; n < 9; ++n) {
        float av[32];
#pragma unroll
        for (int s = 0; s < 4; ++s) {
            int slab = 9 + n * 4 + s;
            if (slab + 1 < NSLAB) STAGE(slab + 1, bufp ^ 1)
            if (s == 0) {
                float dy = sRaw[(2 * n) * 66 + pxl];
                float dx = sRaw[(2 * n + 1) * 66 + pxl];
                float mk = sRaw[(18 + n) * 66 + pxl];
                float py = (float)(hI - 1 + n / 3) + dy;
                float px = (float)(wI - 1 + n % 3) + dx;
                float y0f = floorf(py), x0f = floorf(px);
                float fy = py - y0f, fxv = px - x0f;
                int y0 = (int)y0f, x0 = (int)x0f;
                float wy0 = (1.f - fy) * mk, wy1 = fy * mk, fx1 = 1.f - fxv;
#pragma unroll
                for (int j = 0; j < 32; ++j) av[j] = 0.f;
#pragma unroll
                for (int k = 0; k < 4; ++k) {
                    int yy = y0 + (k >> 1), xx = x0 + (k & 1);
                    bool vld = ((unsigned)yy < HIMG) && ((unsigned)xx < WIMG);
                    float wk = ((k >> 1) ? wy1 : wy0) * ((k & 1) ? fxv : fx1);
                    if (!vld) wk = 0.f;
                    int yc = min(max(yy, 0), HIMG - 1);
                    int xc = min(max(xx, 0), WIMG - 1);
                    int ly = yc - h0 + 2, lx = xc - w0 + 2;
                    if (((unsigned)ly < HY2) && ((unsigned)lx < HX2)) {
                        int r = ly * HX2 + lx;
                        const unsigned short* hb = &sH[r * 128];
                        int xr = r & 7;
                        u32x4 u0 = *(const u32x4*)&hb[((0 + qd) ^ xr) * 8];
                        u32x4 u1 = *(const u32x4*)&hb[((4 + qd) ^ xr) * 8];
                        u32x4 u2 = *(const u32x4*)&hb[((8 + qd) ^ xr) * 8];
                        u32x4 u3 = *(const u32x4*)&hb[((12 + qd) ^ xr) * 8];
                        ACC8(u0, 0) ACC8(u1, 8) ACC8(u2, 16) ACC8(u3, 24)
                    } else if (wk != 0.f) {          // rare: offset beyond halo
                        const unsigned short* src = &yb[(size_t)(yc * WIMG + xc) * 128 + qd * 8];
                        u32x4 u0 = *(const u32x4*)src;
                        u32x4 u1 = *(const u32x4*)(src + 32);
                        u32x4 u2 = *(const u32x4*)(src + 64);
                        u32x4 u3 = *(const u32x4*)(src + 96);
                        ACC8(u0, 0) ACC8(u1, 8) ACC8(u2, 16) ACC8(u3, 24)
                    }
                }
            }
            // pack this k-step's B-frag, 8 ds_read af + 8 MFMA
            unsigned pk0, pk1, pk2, pk3;
            asm("v_cvt_pk_bf16_f32 %0, %1, %2" : "=v"(pk0) : "v"(av[s * 8 + 0]), "v"(av[s * 8 + 1]));
            asm("v_cvt_pk_bf16_f32 %0, %1, %2" : "=v"(pk1) : "v"(av[s * 8 + 2]), "v"(av[s * 8 + 3]));
            asm("v_cvt_pk_bf16_f32 %0, %1, %2" : "=v"(pk2) : "v"(av[s * 8 + 4]), "v"(av[s * 8 + 5]));
            asm("v_cvt_pk_bf16_f32 %0, %1, %2" : "=v"(pk3) : "v"(av[s * 8 + 6]), "v"(av[s * 8 + 7]));
            short8 bfv = __builtin_bit_cast(short8, (u32x4){pk0, pk1, pk2, pk3});
#pragma unroll
            for (int mt = 0; mt < 8; ++mt) {
                short8 af = *(const short8*)&sAf[bufp][mt * 512 + lane * 8];
                acc[mt] = BMFMA(af, bfv, acc[mt]);
            }
            if (n == 8 && s == 3) {
                // z epilogue: bn2 + silu -> pixel-major bf16 (reuse sH)
                unsigned short* sE = sH;
#pragma unroll
                for (int mt = 0; mt < 8; ++mt)
#pragma unroll
                    for (int r4 = 0; r4 < 4; ++r4) {
                        int o = mt * 16 + qd * 4 + r4;
                        float sv = silu_f(acc[mt][r4] + bias2[o]);
                        sE[pxl * 136 + o] = f2b(sv);
                    }
            }
            __syncthreads();
            bufp ^= 1;
        }
    }

    // ---- cv2 phase: slabs 45..52 (8 mt rows each) ----
    const unsigned short* sE = sH;
    f32x4 c2[16];
#pragma unroll
    for (int mt = 0; mt < 16; ++mt) c2[mt] = (f32x4){0.f, 0.f, 0.f, 0.f};
#pragma unroll
    for (int h2 = 0; h2 < 8; ++h2) {
        int slab = 45 + h2;
        if (slab + 1 < NSLAB) STAGE(slab + 1, bufp ^ 1)
        int ks = h2 >> 1, half = h2 & 1;
        short8 bf = *(const short8*)&sE[pxl * 136 + ks * 32 + qd * 8];
#pragma unroll
        for (int mt = 0; mt < 8; ++mt) {
            short8 af = *(const short8*)&sAf[bufp][mt * 512 + lane * 8];
            c2[half * 8 + mt] = BMFMA(af, bf, c2[half * 8 + mt]);
        }
        __syncthreads();
        bufp ^= 1;
    }
    int p = (h0 + w) * WIMG + w0 + n16;
    const float* xb = x + (size_t)b * 256 * HWSZ;
    float* ob = out + (size_t)b * 256 * HWSZ;
#pragma unroll
    for (int mt = 0; mt < 16; ++mt)
#pragma unroll
        for (int r4 = 0; r4 < 4; ++r4) {
            int o = mt * 16 + qd * 4 + r4;
            size_t idx = (size_t)o * HWSZ + p;
            ob[idx] = xb[idx] + silu_f(c2[mt][r4] + bias3[o]);
        }
}

extern "C" void kernel_launch(void* const* d_in, const int* in_sizes, int n_in,
                              void* d_out, int out_size, void* d_ws, size_t ws_size,
                              hipStream_t stream) {
    const float* x     = (const float*)d_in[0];
    const float* cv1w  = (const float*)d_in[1];
    const float* bn1g  = (const float*)d_in[2];
    const float* bn1b  = (const float*)d_in[3];
    const float* bn1m  = (const float*)d_in[4];
    const float* bn1v  = (const float*)d_in[5];
    const float* offw  = (const float*)d_in[6];
    const float* offb  = (const float*)d_in[7];
    const float* dcnw  = (const float*)d_in[8];
    const float* dcnb  = (const float*)d_in[9];
    const float* bn2g  = (const float*)d_in[10];
    const float* bn2b  = (const float*)d_in[11];
    const float* bn2m  = (const float*)d_in[12];
    const float* bn2v  = (const float*)d_in[13];
    const float* cv2w  = (const float*)d_in[14];
    const float* bn3g  = (const float*)d_in[15];
    const float* bn3b  = (const float*)d_in[16];
    const float* bn3m  = (const float*)d_in[17];
    const float* bn3v  = (const float*)d_in[18];
    float* out = (float*)d_out;

    // workspace layout (float units)
    float* base = (float*)d_ws;
    unsigned short* y1t = (unsigned short*)base;                 // 8*6400*128 bf16
    unsigned short* apk1 = (unsigned short*)(base + 7936000);
    unsigned short* apko = (unsigned short*)(base + 7952384);
    unsigned short* apkd = (unsigned short*)(base + 7970816);
    unsigned short* apk2 = (unsigned short*)(base + 8044544);
    float* bias1 = base + 8060928;
    float* biaso = base + 8061056;
    float* bias2 = base + 8061088;
    float* bias3 = base + 8061216;

    k_prep<<<979, 256, 0, stream>>>(cv1w, bn1g, bn1b, bn1m, bn1v,
                                    offw, offb, dcnw, dcnb,
                                    bn2g, bn2b, bn2m, bn2v,
                                    cv2w, bn3g, bn3b, bn3m, bn3v,
                                    apk1, apko, apkd, apk2,
                                    bias1, biaso, bias2, bias3);
    k_cv1<<<800, 256, 0, stream>>>(x, apk1, bias1, y1t);
    k_odc<<<800, 256, 0, stream>>>(y1t, apko, biaso, apkd, bias2,
                                   apk2, bias3, x, out);
}

// Round 11
// 237.125 us; speedup vs baseline: 1.0486x; 1.0343x over previous
//
#include <hip/hip_runtime.h>
#include <math.h>

#define HWSZ 6400
#define WIMG 80
#define HIMG 80
#define BEPS 1e-5f

typedef __attribute__((ext_vector_type(8))) short short8;
typedef __attribute__((ext_vector_type(4))) float f32x4;
typedef __attribute__((ext_vector_type(4))) unsigned u32x4;

__device__ __forceinline__ unsigned short f2b(float f) {
    unsigned u = __builtin_bit_cast(unsigned, f);
    u += 0x7fffu + ((u >> 16) & 1u);
    return (unsigned short)(u >> 16);
}
__device__ __forceinline__ float silu_f(float t) { return t / (1.f + __expf(-t)); }

#define BMFMA(a, b, c) __builtin_amdgcn_mfma_f32_16x16x32_bf16(a, b, c, 0, 0, 0)

// async global->LDS DMA, 16B per lane; LDS dest = wave-uniform base + lane*16
__device__ __forceinline__ void gload16(const unsigned short* g, unsigned short* l) {
    __builtin_amdgcn_global_load_lds(
        (const __attribute__((address_space(1))) unsigned int*)g,
        (__attribute__((address_space(3))) unsigned int*)l, 16, 0, 0);
}

// ---------------- prep: BN-fold + bf16 A-fragment prepack -------------------
// apko [36 ks][2 mi][64][8], apkd [36 ks][8 mt][64][8], apk2 [4 ks][16 mt][64][8]
__global__ __launch_bounds__(256) void k_prep(
    const float* __restrict__ cv1w, const float* __restrict__ g1, const float* __restrict__ b1,
    const float* __restrict__ m1, const float* __restrict__ v1,
    const float* __restrict__ offw, const float* __restrict__ offb,
    const float* __restrict__ dcnw, const float* __restrict__ dcnb,
    const float* __restrict__ g2, const float* __restrict__ b2,
    const float* __restrict__ m2, const float* __restrict__ v2,
    const float* __restrict__ cv2w, const float* __restrict__ g3, const float* __restrict__ b3,
    const float* __restrict__ m3, const float* __restrict__ v3,
    unsigned short* __restrict__ apk1, unsigned short* __restrict__ apko,
    unsigned short* __restrict__ apkd, unsigned short* __restrict__ apk2,
    float* __restrict__ bias1, float* __restrict__ biaso,
    float* __restrict__ bias2, float* __restrict__ bias3)
{
    int idx = blockIdx.x * 256 + threadIdx.x;
    if (idx < 32768) {                       // cv1: [8 mt][8 ks][64][8], K = 256 ch
        int j = idx & 7, L = (idx >> 3) & 63, ks = (idx >> 9) & 7, mt = idx >> 12;
        int o = mt * 16 + (L & 15), k = ks * 32 + (L >> 4) * 8 + j;
        float inv = g1[o] * rsqrtf(v1[o] + BEPS);
        apk1[idx] = f2b(cv1w[o * 256 + k] * inv);
    } else if (idx < 69632) {                // off -> [ks][mi]
        int t = idx - 32768;
        int j = t & 7, L = (t >> 3) & 63;
        int mt = t / 18432, rem = t % 18432, ks = rem >> 9;
        int o = mt * 16 + (L & 15);
        int kp = ks * 32 + (L >> 4) * 8 + j;
        int n = kp >> 7, c = kp & 127;
        float wv = (o < 27) ? offw[(size_t)(o * 128 + c) * 9 + n] : 0.f;
        apko[((size_t)(ks * 2 + mt) * 64 + L) * 8 + j] = f2b(wv);
    } else if (idx < 217088) {               // dcn -> [ks][mt], BN2 fold
        int t = idx - 69632;
        int j = t & 7, L = (t >> 3) & 63;
        int mt = t / 18432, rem = t % 18432, ks = rem >> 9;
        int o = mt * 16 + (L & 15);
        int kp = ks * 32 + (L >> 4) * 8 + j;
        int n = kp >> 7, c = kp & 127;
        float inv = g2[o] * rsqrtf(v2[o] + BEPS);
        apkd[((size_t)(ks * 8 + mt) * 64 + L) * 8 + j] = f2b(dcnw[(size_t)(o * 128 + c) * 9 + n] * inv);
    } else if (idx < 249856) {               // cv2 -> [ks][mt], BN3 fold
        int t = idx - 217088;
        int j = t & 7, L = (t >> 3) & 63, ks = (t >> 9) & 3, mt = t >> 11;
        int o = mt * 16 + (L & 15), k = ks * 32 + (L >> 4) * 8 + j;
        float inv = g3[o] * rsqrtf(v3[o] + BEPS);
        apk2[((size_t)(ks * 16 + mt) * 64 + L) * 8 + j] = f2b(cv2w[o * 128 + k] * inv);
    } else if (idx < 250395) {               // biases
        int t = idx - 249856;
        if (t < 128) { float inv = g1[t] * rsqrtf(v1[t] + BEPS); bias1[t] = b1[t] - m1[t] * inv; }
        else if (t < 155) { biaso[t - 128] = offb[t - 128]; }
        else if (t < 283) { int o = t - 155; float inv = g2[o] * rsqrtf(v2[o] + BEPS);
                            bias2[o] = dcnb[o] * inv + b2[o] - m2[o] * inv; }
        else { int o = t - 283; float inv = g3[o] * rsqrtf(v3[o] + BEPS); bias3[o] = b3[o] - m3[o] * inv; }
    }
}

// ---------------- cv1: 1x1 (256->128) + bn1 + silu -> y1t (pixel-major bf16) ----
// r9 version (best measured): af hoisted to regs; staging = 64 coalesced scalar
// loads + f2b + 8 packed ds_write_b128 per thread.
__global__ __launch_bounds__(256) void k_cv1(
    const float* __restrict__ x, const unsigned short* __restrict__ apk1,
    const float* __restrict__ bias1, unsigned short* __restrict__ y1t)
{
    __shared__ __align__(16) unsigned short sB[20480];
    int blk = blockIdx.x;
    int b = blk / 100, pt = blk % 100;
    int p0 = pt * 64;
    int tid = threadIdx.x;
    int lane = tid & 63;
    int w = tid >> 6;
    // hoist all 16 A-fragments (64 KB table, L2-hot) into registers
    short8 af0[8], af1[8];
#pragma unroll
    for (int ks = 0; ks < 8; ++ks) {
        af0[ks] = *(const short8*)&apk1[(size_t)(((w * 2 + 0) * 8 + ks) * 64 + lane) * 8];
        af1[ks] = *(const short8*)&apk1[(size_t)(((w * 2 + 1) * 8 + ks) * 64 + lane) * 8];
    }
    {
        int px = lane, q = w;
        const float* xb = x + (size_t)b * 256 * HWSZ + p0 + px;
        for (int ks = 0; ks < 8; ++ks) {
            short8 v;
#pragma unroll
            for (int j = 0; j < 8; ++j)
                v[j] = (short)f2b(xb[(size_t)(ks * 32 + q * 8 + j) * HWSZ]);
            *(short8*)&sB[((ks * 4 + (px >> 4)) * 16 + (px & 15)) * 40 + q * 8] = v;
        }
    }
    __syncthreads();
    int n16 = lane & 15, qd = lane >> 4;
    f32x4 acc[2][4];
#pragma unroll
    for (int mi = 0; mi < 2; ++mi)
#pragma unroll
        for (int nt = 0; nt < 4; ++nt) acc[mi][nt] = (f32x4){0.f, 0.f, 0.f, 0.f};
#pragma unroll
    for (int ks = 0; ks < 8; ++ks) {
        short8 bf[4];
#pragma unroll
        for (int nt = 0; nt < 4; ++nt)
            bf[nt] = *(const short8*)&sB[((ks * 4 + nt) * 16 + n16) * 40 + qd * 8];
#pragma unroll
        for (int nt = 0; nt < 4; ++nt) acc[0][nt] = BMFMA(af0[ks], bf[nt], acc[0][nt]);
#pragma unroll
        for (int nt = 0; nt < 4; ++nt) acc[1][nt] = BMFMA(af1[ks], bf[nt], acc[1][nt]);
    }
    __syncthreads();
#pragma unroll
    for (int mi = 0; mi < 2; ++mi)
#pragma unroll
        for (int nt = 0; nt < 4; ++nt)
#pragma unroll
            for (int r = 0; r < 4; ++r) {
                int o = w * 32 + mi * 16 + qd * 4 + r;
                float sv = silu_f(acc[mi][nt][r] + bias1[o]);
                sB[(nt * 16 + n16) * 136 + o] = f2b(sv);
            }
    __syncthreads();
    {
        int px = tid >> 2, qq = tid & 3;
        unsigned short* ytb = y1t + ((size_t)b * HWSZ + p0 + px) * 128;
#pragma unroll
        for (int seg = 0; seg < 4; ++seg) {
            short8 v = *(const short8*)&sB[px * 136 + qq * 32 + seg * 8];
            *(short8*)&ytb[qq * 32 + seg * 8] = v;
        }
    }
}

// ---------------- odc: fused off + DCNv2 + bn2 + silu + cv2 + residual -------
// round-6 structure (best measured, reproduced twice at 108.4-108.6 us):
// 8x20 halo staged once (XOR-swizzled), af slabs via global_load_lds
// ping-pong, plain __syncthreads.
#define HY2 8
#define HX2 20
#define NH 160
#define NSLAB 53

#define ACC8(uu, cb)                                                                   \
    {                                                                                  \
        _Pragma("unroll") for (int t = 0; t < 4; ++t) {                                \
            unsigned uv = (uu)[t];                                                     \
            av[(cb) + 2 * t] = fmaf(wk, __builtin_bit_cast(float, uv << 16),           \
                                    av[(cb) + 2 * t]);                                 \
            av[(cb) + 2 * t + 1] = fmaf(wk, __builtin_bit_cast(float, uv & 0xffff0000u),\
                                        av[(cb) + 2 * t + 1]);                         \
        }                                                                              \
    }

__device__ __forceinline__ const unsigned short* slab_src(
    const unsigned short* apko, const unsigned short* apkd,
    const unsigned short* apk2, int i) {
    if (i < 9)  return apko + (size_t)i * 4096;
    if (i < 45) return apkd + (size_t)(i - 9) * 4096;
    return apk2 + (size_t)(i - 45) * 4096;
}

#define STAGE(i, bp)                                                                   \
    {                                                                                  \
        const unsigned short* src_ = slab_src(apko, apkd, apk2, (i));                  \
        gload16(src_ + ((w * 2 + 0) * 512 + lane * 8), &sAf[bp][(w * 2 + 0) * 512]);   \
        gload16(src_ + ((w * 2 + 1) * 512 + lane * 8), &sAf[bp][(w * 2 + 1) * 512]);   \
    }

__global__ __launch_bounds__(256, 2) void k_odc(
    const unsigned short* __restrict__ y1t,
    const unsigned short* __restrict__ apko, const float* __restrict__ biaso,
    const unsigned short* __restrict__ apkd, const float* __restrict__ bias2,
    const unsigned short* __restrict__ apk2, const float* __restrict__ bias3,
    const float* __restrict__ x, float* __restrict__ out)
{
    __shared__ __align__(16) unsigned short sH[NH * 128];    // 40,960 B halo / z-buf
    __shared__ float sRaw[27 * 66];                          //  7,128 B
    __shared__ __align__(16) unsigned short sAf[2][4096];    // 16,384 B af ping-pong

    int blk = blockIdx.x;
    int b = blk / 100, pt = blk % 100;
    int h0 = (pt / 5) * 4, w0 = (pt % 5) * 16;
    int tid = threadIdx.x, lane = tid & 63, w = tid >> 6;
    int n16 = lane & 15, qd = lane >> 4;
    int pxl = w * 16 + n16;
    const unsigned short* yb = y1t + (size_t)b * HWSZ * 128;

    // ---- stage halo (8x20 rows, XOR-swizzled dest) + first af slab ----
    for (int i = tid; i < NH * 16; i += 256) {
        int r = i >> 4, u = i & 15;
        int ly = r / HX2, lx = r % HX2;
        int yy = min(max(h0 + ly - 2, 0), HIMG - 1);
        int xx = min(max(w0 + lx - 2, 0), WIMG - 1);
        *(u32x4*)&sH[r * 128 + ((u ^ (r & 7)) * 8)] =
            *(const u32x4*)&yb[(size_t)(yy * WIMG + xx) * 128 + u * 8];
    }
    STAGE(0, 0)
    __syncthreads();                          // halo + slab0 ready
    int bufp = 0;

    // ---- off phase: slabs 0..8 (one per tap); raw -> LDS ----
    {
        f32x4 oa0 = (f32x4){0.f, 0.f, 0.f, 0.f};
        f32x4 oa1 = (f32x4){0.f, 0.f, 0.f, 0.f};
        for (int n = 0; n < 9; ++n) {
            STAGE(n + 1, bufp ^ 1)
            int dh = n / 3 - 1, dw = n % 3 - 1;
            int hh = h0 + w + dh, ww = w0 + n16 + dw;
            bool valid = ((unsigned)hh < HIMG) && ((unsigned)ww < WIMG);
            int r = (w + 2 + dh) * HX2 + (n16 + 2 + dw);
            int xr = r & 7;
            const unsigned short* hb = &sH[r * 128];
#pragma unroll
            for (int s = 0; s < 4; ++s) {
                short8 bf = *(const short8*)&hb[((s * 4 + qd) ^ xr) * 8];
                if (!valid) bf = (short8){0, 0, 0, 0, 0, 0, 0, 0};
                short8 a0 = *(const short8*)&sAf[bufp][(s * 2 + 0) * 512 + lane * 8];
                short8 a1 = *(const short8*)&sAf[bufp][(s * 2 + 1) * 512 + lane * 8];
                oa0 = BMFMA(a0, bf, oa0);
                oa1 = BMFMA(a1, bf, oa1);
            }
            if (n == 8) {
#pragma unroll
                for (int mi = 0; mi < 2; ++mi)
#pragma unroll
                    for (int r4 = 0; r4 < 4; ++r4) {
                        int o = mi * 16 + qd * 4 + r4;
                        if (o < 27) {
                            float t = (mi ? oa1[r4] : oa0[r4]) + biaso[o];
                            if (o >= 18) t = 1.f / (1.f + __expf(-t));
                            sRaw[o * 66 + pxl] = t;
                        }
                    }
            }
            __syncthreads();
            bufp ^= 1;
        }
    }

    // ---- dcn phase: slabs 9..44; gather from LDS halo (global fallback) ----
    f32x4 acc[8];
#pragma unroll
    for (int mt = 0; mt < 8; ++mt) acc[mt] = (f32x4){0.f, 0.f, 0.f, 0.f};
    int hI = h0 + w, wI = w0 + n16;

    for (int n = 0; n < 9; ++n) {
        float av[32];
#pragma unroll
        for (int s = 0; s < 4; ++s) {
            int slab = 9 + n * 4 + s;
            if (slab + 1 < NSLAB) STAGE(slab + 1, bufp ^ 1)
            if (s == 0) {
                float dy = sRaw[(2 * n) * 66 + pxl];
                float dx = sRaw[(2 * n + 1) * 66 + pxl];
                float mk = sRaw[(18 + n) * 66 + pxl];
                float py = (float)(hI - 1 + n / 3) + dy;
                float px = (float)(wI - 1 + n % 3) + dx;
                float y0f = floorf(py), x0f = floorf(px);
                float fy = py - y0f, fxv = px - x0f;
                int y0 = (int)y0f, x0 = (int)x0f;
                float wy0 = (1.f - fy) * mk, wy1 = fy * mk, fx1 = 1.f - fxv;
#pragma unroll
                for (int j = 0; j < 32; ++j) av[j] = 0.f;
#pragma unroll
                for (int k = 0; k < 4; ++k) {
                    int yy = y0 + (k >> 1), xx = x0 + (k & 1);
                    bool vld = ((unsigned)yy < HIMG) && ((unsigned)xx < WIMG);
                    float wk = ((k >> 1) ? wy1 : wy0) * ((k & 1) ? fxv : fx1);
                    if (!vld) wk = 0.f;
                    int yc = min(max(yy, 0), HIMG - 1);
                    int xc = min(max(xx, 0), WIMG - 1);
                    int ly = yc - h0 + 2, lx = xc - w0 + 2;
                    if (((unsigned)ly < HY2) && ((unsigned)lx < HX2)) {
                        int r = ly * HX2 + lx;
                        const unsigned short* hb = &sH[r * 128];
                        int xr = r & 7;
                        u32x4 u0 = *(const u32x4*)&hb[((0 + qd) ^ xr) * 8];
                        u32x4 u1 = *(const u32x4*)&hb[((4 + qd) ^ xr) * 8];
                        u32x4 u2 = *(const u32x4*)&hb[((8 + qd) ^ xr) * 8];
                        u32x4 u3 = *(const u32x4*)&hb[((12 + qd) ^ xr) * 8];
                        ACC8(u0, 0) ACC8(u1, 8) ACC8(u2, 16) ACC8(u3, 24)
                    } else if (wk != 0.f) {          // rare: offset beyond halo
                        const unsigned short* src = &yb[(size_t)(yc * WIMG + xc) * 128 + qd * 8];
                        u32x4 u0 = *(const u32x4*)src;
                        u32x4 u1 = *(const u32x4*)(src + 32);
                        u32x4 u2 = *(const u32x4*)(src + 64);
                        u32x4 u3 = *(const u32x4*)(src + 96);
                        ACC8(u0, 0) ACC8(u1, 8) ACC8(u2, 16) ACC8(u3, 24)
                    }
                }
            }
            // pack this k-step's B-frag, 8 ds_read af + 8 MFMA
            unsigned pk0, pk1, pk2, pk3;
            asm("v_cvt_pk_bf16_f32 %0, %1, %2" : "=v"(pk0) : "v"(av[s * 8 + 0]), "v"(av[s * 8 + 1]));
            asm("v_cvt_pk_bf16_f32 %0, %1, %2" : "=v"(pk1) : "v"(av[s * 8 + 2]), "v"(av[s * 8 + 3]));
            asm("v_cvt_pk_bf16_f32 %0, %1, %2" : "=v"(pk2) : "v"(av[s * 8 + 4]), "v"(av[s * 8 + 5]));
            asm("v_cvt_pk_bf16_f32 %0, %1, %2" : "=v"(pk3) : "v"(av[s * 8 + 6]), "v"(av[s * 8 + 7]));
            short8 bfv = __builtin_bit_cast(short8, (u32x4){pk0, pk1, pk2, pk3});
#pragma unroll
            for (int mt = 0; mt < 8; ++mt) {
                short8 af = *(const short8*)&sAf[bufp][mt * 512 + lane * 8];
                acc[mt] = BMFMA(af, bfv, acc[mt]);
            }
            if (n == 8 && s == 3) {
                // z epilogue: bn2 + silu -> pixel-major bf16 (reuse sH)
                unsigned short* sE = sH;
#pragma unroll
                for (int mt = 0; mt < 8; ++mt)
#pragma unroll
                    for (int r4 = 0; r4 < 4; ++r4) {
                        int o = mt * 16 + qd * 4 + r4;
                        float sv = silu_f(acc[mt][r4] + bias2[o]);
                        sE[pxl * 136 + o] = f2b(sv);
                    }
            }
            __syncthreads();
            bufp ^= 1;
        }
    }

    // ---- cv2 phase: slabs 45..52 (8 mt rows each) ----
    const unsigned short* sE = sH;
    f32x4 c2[16];
#pragma unroll
    for (int mt = 0; mt < 16; ++mt) c2[mt] = (f32x4){0.f, 0.f, 0.f, 0.f};
#pragma unroll
    for (int h2 = 0; h2 < 8; ++h2) {
        int slab = 45 + h2;
        if (slab + 1 < NSLAB) STAGE(slab + 1, bufp ^ 1)
        int ks = h2 >> 1, half = h2 & 1;
        short8 bf = *(const short8*)&sE[pxl * 136 + ks * 32 + qd * 8];
#pragma unroll
        for (int mt = 0; mt < 8; ++mt) {
            short8 af = *(const short8*)&sAf[bufp][mt * 512 + lane * 8];
            c2[half * 8 + mt] = BMFMA(af, bf, c2[half * 8 + mt]);
        }
        __syncthreads();
        bufp ^= 1;
    }
    int p = (h0 + w) * WIMG + w0 + n16;
    const float* xb = x + (size_t)b * 256 * HWSZ;
    float* ob = out + (size_t)b * 256 * HWSZ;
#pragma unroll
    for (int mt = 0; mt < 16; ++mt)
#pragma unroll
        for (int r4 = 0; r4 < 4; ++r4) {
            int o = mt * 16 + qd * 4 + r4;
            size_t idx = (size_t)o * HWSZ + p;
            ob[idx] = xb[idx] + silu_f(c2[mt][r4] + bias3[o]);
        }
}

extern "C" void kernel_launch(void* const* d_in, const int* in_sizes, int n_in,
                              void* d_out, int out_size, void* d_ws, size_t ws_size,
                              hipStream_t stream) {
    const float* x     = (const float*)d_in[0];
    const float* cv1w  = (const float*)d_in[1];
    const float* bn1g  = (const float*)d_in[2];
    const float* bn1b  = (const float*)d_in[3];
    const float* bn1m  = (const float*)d_in[4];
    const float* bn1v  = (const float*)d_in[5];
    const float* offw  = (const float*)d_in[6];
    const float* offb  = (const float*)d_in[7];
    const float* dcnw  = (const float*)d_in[8];
    const float* dcnb  = (const float*)d_in[9];
    const float* bn2g  = (const float*)d_in[10];
    const float* bn2b  = (const float*)d_in[11];
    const float* bn2m  = (const float*)d_in[12];
    const float* bn2v  = (const float*)d_in[13];
    const float* cv2w  = (const float*)d_in[14];
    const float* bn3g  = (const float*)d_in[15];
    const float* bn3b  = (const float*)d_in[16];
    const float* bn3m  = (const float*)d_in[17];
    const float* bn3v  = (const float*)d_in[18];
    float* out = (float*)d_out;

    // workspace layout (float units)
    float* base = (float*)d_ws;
    unsigned short* y1t = (unsigned short*)base;                 // 8*6400*128 bf16
    unsigned short* apk1 = (unsigned short*)(base + 7936000);
    unsigned short* apko = (unsigned short*)(base + 7952384);
    unsigned short* apkd = (unsigned short*)(base + 7970816);
    unsigned short* apk2 = (unsigned short*)(base + 8044544);
    float* bias1 = base + 8060928;
    float* biaso = base + 8061056;
    float* bias2 = base + 8061088;
    float* bias3 = base + 8061216;

    k_prep<<<979, 256, 0, stream>>>(cv1w, bn1g, bn1b, bn1m, bn1v,
                                    offw, offb, dcnw, dcnb,
                                    bn2g, bn2b, bn2m, bn2v,
                                    cv2w, bn3g, bn3b, bn3m, bn3v,
                                    apk1, apko, apkd, apk2,
                                    bias1, biaso, bias2, bias3);
    k_cv1<<<800, 256, 0, stream>>>(x, apk1, bias1, y1t);
    k_odc<<<800, 256, 0, stream>>>(y1t, apko, biaso, apkd, bias2,
                                   apk2, bias3, x, out);
}